// Round 1
// baseline (587.770 us; speedup 1.0000x reference)
//
#include <hip/hip_runtime.h>
#include <math.h>

// Problem constants
#define Bq 2
#define Nn 20000
#define Ee 20000
#define Aa 8
#define Hh 256
#define TEe 32
constexpr int BE   = Bq * Ee;   // 40000 edges total
constexpr int BN   = Bq * Nn;   // 40000 nodes total
constexpr int KENC = Hh + TEe;  // 288
constexpr int KUPD = 2 * Hh;    // 512
constexpr int EPB  = 16;        // edges per block
constexpr int NPB  = 16;        // nodes per block

__device__ __forceinline__ float gelu_f(float x) {
    return 0.5f * x * (1.f + erff(x * 0.70710678118654752440f));
}

__device__ __forceinline__ float wred(float v) {
    v += __shfl_xor(v, 1, 64);
    v += __shfl_xor(v, 2, 64);
    v += __shfl_xor(v, 4, 64);
    v += __shfl_xor(v, 8, 64);
    v += __shfl_xor(v, 16, 64);
    v += __shfl_xor(v, 32, 64);
    return v;
}

// mask dtype sniffing: flag bit1 => float32 mask, bit0 => uint8 mask, none => int32
__device__ __forceinline__ float mask_at(const void* mp, int flag, int i) {
    if (flag & 2) return ((const float*)mp)[i];
    if (flag & 1) return ((const unsigned char*)mp)[i] ? 1.f : 0.f;
    return ((const int*)mp)[i] ? 1.f : 0.f;
}

__global__ void k_zero(float4* p, int n4) {
    int i = blockIdx.x * blockDim.x + threadIdx.x;
    int stride = gridDim.x * blockDim.x;
    float4 z; z.x = 0.f; z.y = 0.f; z.z = 0.f; z.w = 0.f;
    for (; i < n4; i += stride) p[i] = z;
}

// Scan the first (BE*Aa) BYTES of the mask buffer read as u32 words — safe
// under u8 (whole buffer), i32/f32 (first quarter). Values observed:
//  i32 mask: words in {0,1}
//  u8  mask: words are 4 packed 0/1 bytes (never 0x3F800000)
//  f32 mask: words in {0, 0x3F800000}
__global__ void k_detect(const unsigned int* mw, int n, int* flag) {
    int found = 0;
    for (int i = blockIdx.x * blockDim.x + threadIdx.x; i < n;
         i += gridDim.x * blockDim.x) {
        unsigned int w = mw[i];
        if (w == 0x3F800000u) found |= 2;
        else if (w > 1u) found |= 1;
    }
    __shared__ int sf;
    if (threadIdx.x == 0) sf = 0;
    __syncthreads();
    if (found) atomicOr(&sf, found);
    __syncthreads();
    if (threadIdx.x == 0 && sf) atomicOr(flag, sf);
}

// Edge phase: pool members -> concat type emb -> @W_enc + b -> gelu -> LN
// -> atomic scatter into upd/cnt.  One block handles EPB edges, 256 threads
// (thread = output channel h).
__global__ __launch_bounds__(256) void k_edge(
    const float* __restrict__ nf, const int* __restrict__ members,
    const int* __restrict__ types, const void* __restrict__ maskp,
    const float* __restrict__ ett, const float* __restrict__ Wenc,
    const float* __restrict__ benc, const float* __restrict__ genc,
    const float* __restrict__ beenc, const int* __restrict__ flagp,
    float* __restrict__ upd, float* __restrict__ cnt) {
    __shared__ float s_in[EPB][KENC];      // 18 KB: pooled+emb rows, reused for g
    __shared__ int   s_idx[EPB][Aa];
    __shared__ float s_m[EPB][Aa];
    __shared__ float s_cnt[EPB];
    __shared__ float s_stats[EPB][2];

    const int tid = threadIdx.x;
    const int e0  = blockIdx.x * EPB;
    const int flag = flagp[0];

    if (tid < EPB * Aa) {
        int e = tid >> 3, a = tid & 7;
        int ge = e0 + e;
        int idx = members[ge * Aa + a];
        idx = min(max(idx, 0), Nn - 1);
        s_idx[e][a] = idx;
        s_m[e][a] = mask_at(maskp, flag, ge * Aa + a);
    }
    __syncthreads();
    if (tid < EPB) {
        float c = 0.f;
        #pragma unroll
        for (int a = 0; a < Aa; a++) c += s_m[tid][a];
        s_cnt[tid] = fmaxf(c, 1.f);
    }
    __syncthreads();

    // pooled features (masked mean) + type embedding
    for (int e = 0; e < EPB; e++) {
        int ge = e0 + e;
        int b = ge / Ee;
        const float* nfb = nf + (size_t)b * Nn * Hh;
        float acc = 0.f;
        #pragma unroll
        for (int a = 0; a < Aa; a++) {
            float m = s_m[e][a];
            if (m != 0.f) acc += m * nfb[(size_t)s_idx[e][a] * Hh + tid];
        }
        s_in[e][tid] = acc / s_cnt[e];
    }
    if (tid < TEe) {
        for (int e = 0; e < EPB; e++) {
            int t = types[e0 + e];
            s_in[e][Hh + tid] = ett[t * TEe + tid];
        }
    }
    __syncthreads();

    // x = in @ W_enc + b_enc   (thread owns column h = tid for all EPB edges)
    float acc[EPB];
    {
        float bb = benc[tid];
        #pragma unroll
        for (int e = 0; e < EPB; e++) acc[e] = bb;
    }
    for (int k = 0; k < KENC; k += 4) {
        float w0 = Wenc[(k + 0) * Hh + tid];
        float w1 = Wenc[(k + 1) * Hh + tid];
        float w2 = Wenc[(k + 2) * Hh + tid];
        float w3 = Wenc[(k + 3) * Hh + tid];
        #pragma unroll
        for (int e = 0; e < EPB; e++) {
            float4 iv = *(const float4*)&s_in[e][k];
            acc[e] = fmaf(iv.x, w0, acc[e]);
            acc[e] = fmaf(iv.y, w1, acc[e]);
            acc[e] = fmaf(iv.z, w2, acc[e]);
            acc[e] = fmaf(iv.w, w3, acc[e]);
        }
    }
    __syncthreads();   // everyone done reading s_in before reuse

    #pragma unroll
    for (int e = 0; e < EPB; e++) {
        acc[e] = gelu_f(acc[e]);
        s_in[e][tid] = acc[e];   // stash g for the LN reduction
    }
    __syncthreads();

    int lane = tid & 63, wid = tid >> 6;
    for (int e = wid; e < EPB; e += 4) {
        float4 v = *(const float4*)&s_in[e][lane * 4];
        float s  = v.x + v.y + v.z + v.w;
        float s2 = v.x * v.x + v.y * v.y + v.z * v.z + v.w * v.w;
        s = wred(s); s2 = wred(s2);
        if (lane == 0) {
            float mu = s * (1.f / Hh);
            s_stats[e][0] = mu;
            s_stats[e][1] = rsqrtf(s2 * (1.f / Hh) - mu * mu + 1e-5f);
        }
    }
    __syncthreads();

    float gam = genc[tid], bet = beenc[tid];
    #pragma unroll
    for (int e = 0; e < EPB; e++)
        acc[e] = (acc[e] - s_stats[e][0]) * s_stats[e][1] * gam + bet;

    // scatter-add to member nodes
    for (int e = 0; e < EPB; e++) {
        int ge = e0 + e;
        int b = ge / Ee;
        float* updb = upd + (size_t)b * Nn * Hh;
        #pragma unroll
        for (int a = 0; a < Aa; a++) {
            if (s_m[e][a] != 0.f)
                atomicAdd(&updb[(size_t)s_idx[e][a] * Hh + tid], acc[e]);
        }
    }
    if (tid < EPB * Aa) {
        int e = tid >> 3, a = tid & 7;
        int ge = e0 + e;
        int b = ge / Ee;
        if (s_m[e][a] != 0.f)
            atomicAdd(&cnt[b * Nn + s_idx[e][a]], s_m[e][a]);
    }
}

// Node phase: y = gelu(concat(nf, upd/cnt) @ W_upd + b) -> LN -> out
__global__ __launch_bounds__(256) void k_node(
    const float* __restrict__ nf, const float* __restrict__ upd,
    const float* __restrict__ cnt, const float* __restrict__ Wupd,
    const float* __restrict__ bupd, const float* __restrict__ gupd,
    const float* __restrict__ beupd, float* __restrict__ out) {
    __shared__ float s_in[NPB][KUPD];   // 32 KB
    __shared__ float s_stats[NPB][2];
    const int tid = threadIdx.x;
    const int n0  = blockIdx.x * NPB;

    for (int i = 0; i < NPB; i++) {
        int gn = n0 + i;
        s_in[i][tid] = nf[(size_t)gn * Hh + tid];
        float c = fmaxf(cnt[gn], 1.f);
        s_in[i][Hh + tid] = upd[(size_t)gn * Hh + tid] / c;
    }
    __syncthreads();

    float acc[NPB];
    {
        float bb = bupd[tid];
        #pragma unroll
        for (int i = 0; i < NPB; i++) acc[i] = bb;
    }
    for (int k = 0; k < KUPD; k += 4) {
        float w0 = Wupd[(k + 0) * Hh + tid];
        float w1 = Wupd[(k + 1) * Hh + tid];
        float w2 = Wupd[(k + 2) * Hh + tid];
        float w3 = Wupd[(k + 3) * Hh + tid];
        #pragma unroll
        for (int i = 0; i < NPB; i++) {
            float4 iv = *(const float4*)&s_in[i][k];
            acc[i] = fmaf(iv.x, w0, acc[i]);
            acc[i] = fmaf(iv.y, w1, acc[i]);
            acc[i] = fmaf(iv.z, w2, acc[i]);
            acc[i] = fmaf(iv.w, w3, acc[i]);
        }
    }
    __syncthreads();

    #pragma unroll
    for (int i = 0; i < NPB; i++) {
        acc[i] = gelu_f(acc[i]);
        s_in[i][tid] = acc[i];
    }
    __syncthreads();

    int lane = tid & 63, wid = tid >> 6;
    for (int i = wid; i < NPB; i += 4) {
        float4 v = *(const float4*)&s_in[i][lane * 4];
        float s  = v.x + v.y + v.z + v.w;
        float s2 = v.x * v.x + v.y * v.y + v.z * v.z + v.w * v.w;
        s = wred(s); s2 = wred(s2);
        if (lane == 0) {
            float mu = s * (1.f / Hh);
            s_stats[i][0] = mu;
            s_stats[i][1] = rsqrtf(s2 * (1.f / Hh) - mu * mu + 1e-5f);
        }
    }
    __syncthreads();

    float gam = gupd[tid], bet = beupd[tid];
    for (int i = 0; i < NPB; i++) {
        int gn = n0 + i;
        out[(size_t)gn * Hh + tid] =
            (acc[i] - s_stats[i][0]) * s_stats[i][1] * gam + bet;
    }
}

extern "C" void kernel_launch(void* const* d_in, const int* in_sizes, int n_in,
                              void* d_out, int out_size, void* d_ws, size_t ws_size,
                              hipStream_t stream) {
    const float* nf    = (const float*)d_in[0];
    const int* members = (const int*)d_in[1];
    const int* types   = (const int*)d_in[2];
    const void* maskp  = d_in[3];
    const float* ett   = (const float*)d_in[4];
    const float* Wenc  = (const float*)d_in[5];
    const float* benc  = (const float*)d_in[6];
    const float* genc  = (const float*)d_in[7];
    const float* beenc = (const float*)d_in[8];
    const float* Wupd  = (const float*)d_in[9];
    const float* bupd  = (const float*)d_in[10];
    const float* gupd  = (const float*)d_in[11];
    const float* beupd = (const float*)d_in[12];
    float* out = (float*)d_out;

    char* ws = (char*)d_ws;
    int*   flag = (int*)ws;                       // 4 B @ 0
    float* cnt  = (float*)(ws + 256);             // BN floats
    float* upd  = (float*)(ws + 256 + (size_t)BN * 4);  // BN*Hh floats

    // zero flag + cnt + upd  (256 B pad + 41.6 MB), in float4s
    int n4 = (256 + BN * 4 + BN * Hh * 4) / 16;
    hipLaunchKernelGGL(k_zero, dim3(2048), dim3(256), 0, stream,
                       (float4*)ws, n4);
    hipLaunchKernelGGL(k_detect, dim3(512), dim3(256), 0, stream,
                       (const unsigned int*)maskp, BE * Aa / 4, flag);
    hipLaunchKernelGGL(k_edge, dim3(BE / EPB), dim3(256), 0, stream,
                       nf, members, types, maskp, ett, Wenc, benc, genc, beenc,
                       flag, upd, cnt);
    hipLaunchKernelGGL(k_node, dim3(BN / NPB), dim3(256), 0, stream,
                       nf, upd, cnt, Wupd, bupd, gupd, beupd, out);
}